// Round 7
// baseline (10153.288 us; speedup 1.0000x reference)
//
#include <hip/hip_runtime.h>
#include <math.h>

#define BATCH 128
#define CCH 5
#define SEQ 512
#define UNITS 256
#define RU 512

#define ENC_N 33554432   // BATCH*SEQ*RU floats

__device__ __forceinline__ float sigmoidf_(float v) {
    return 1.0f / (1.0f + __expf(-v));
}
__device__ __forceinline__ float tanhf_(float v) {
    float e = __expf(2.0f * v);
    return 1.0f - 2.0f / (e + 1.0f);
}
__device__ __forceinline__ void astoref(float* p, float v) {
    __hip_atomic_store(p, v, __ATOMIC_RELAXED, __HIP_MEMORY_SCOPE_AGENT);
}
__device__ __forceinline__ unsigned long long aloadu64(const unsigned long long* p) {
    return __hip_atomic_load(p, __ATOMIC_RELAXED, __HIP_MEMORY_SCOPE_AGENT);
}
__device__ __forceinline__ int aloadi(const int* p) {
    return __hip_atomic_load(p, __ATOMIC_RELAXED, __HIP_MEMORY_SCOPE_AGENT);
}

// ---------------------------------------------------------------------------
// Encoder: 256 blocks = dir(2) x batch-tile(16, 8 batches) x col-slice(8).
// Wr slice in REGISTERS (16 rows x 2 cols per lane, asm-pinned).
// waves_per_eu(4,4) + LDS pad >80KB force 1 block/CU -> VGPR budget 128 so
// the pinned weights actually stay register-resident (R6: budget 64 -> spill).
// ---------------------------------------------------------------------------
__global__ __attribute__((amdgpu_flat_work_group_size(1024, 1024),
                          amdgpu_waves_per_eu(4, 4)))
void encoder_kernel(const float* __restrict__ x,
                    const float* __restrict__ Wf_k, const float* __restrict__ Wf_r,
                    const float* __restrict__ bf,
                    const float* __restrict__ Wb_k, const float* __restrict__ Wb_r,
                    const float* __restrict__ bb,
                    float* __restrict__ enc, float* __restrict__ h_ex,
                    int* __restrict__ cnt)
{
    const int bid  = blockIdx.x;
    const int dir  = bid >> 7;
    const int tile = (bid >> 3) & 15;
    const int jsl  = bid & 7;
    const int bg0  = tile * 8;
    const float* __restrict__ Wk   = dir ? Wb_k : Wf_k;
    const float* __restrict__ Wr   = dir ? Wb_r : Wf_r;
    const float* __restrict__ bias = dir ? bb : bf;
    const int tid  = threadIdx.x;
    const int wv   = tid >> 6;
    const int lane = tid & 63;
    const int g0 = ((lane >> 5) << 8) + jsl * 32 + (lane & 31);

    __shared__ float zp[8][8][128];                 // 32 KB
    __shared__ float __align__(16) hL[8][UNITS];    // 8 KB
    __shared__ float WkL[5][128];
    __shared__ float biasL[128];
    __shared__ unsigned char mL[8][SEQ];            // 4 KB
    __shared__ float xLe[8][8];
    __shared__ float ldspad[8448];                  // 33 KB: forces 1 block/CU

    // ---- one-time staging ----
    for (int i = tid; i < 8 * UNITS; i += 1024) ((float*)hL)[i] = 0.0f;
    for (int i = tid; i < 8448; i += 1024) ldspad[i] = 0.0f;
    if (tid < 128) biasL[tid] = bias[((tid >> 5) << 8) + jsl * 32 + (tid & 31)];
    if (tid >= 128 && tid < 768) {
        int i = tid - 128, c = i >> 7, cl = i & 127;
        WkL[c][cl] = Wk[c * 1024 + ((cl >> 5) << 8) + jsl * 32 + (cl & 31)];
    }
    for (int i = tid; i < 8 * SEQ; i += 1024) {
        int b = i >> 9, tt = i & (SEQ - 1);
        mL[b][tt] = (x[((size_t)((bg0 + b) * CCH) * SEQ + tt) * 3 + 2] != 0.0f) ? 1 : 0;
    }
    // weights -> registers (pinned): rows 16*wv..+15, cols g0 and g0+512
    float wr0[16], wr1[16];
    {
        const float* wbase = Wr + (size_t)(wv * 16) * 1024 + g0;
        #pragma unroll
        for (int r = 0; r < 16; ++r) {
            wr0[r] = wbase[(size_t)r * 1024];
            wr1[r] = wbase[(size_t)r * 1024 + 512];
        }
        #pragma unroll
        for (int r = 0; r < 16; ++r)
            asm volatile("" : "+v"(wr0[r]), "+v"(wr1[r]));
    }
    float creg = 0.0f;    // c-state for gate threads (tid<256: b=tid>>5,u=tid&31)
    __syncthreads();

    for (int t = 0; t < SEQ; ++t) {
        const int ts = dir ? (SEQ - 1 - t) : t;
        if (t > 0) {
            if (tid == 0) {
                int target = 8 * t, guard = 0;
                while (aloadi(&cnt[dir * 16 + tile]) < target &&
                       guard < (1 << 26)) { __builtin_amdgcn_s_sleep(1); ++guard; }
            }
            __syncthreads();
            {   // h (8x256) from L3, buffer (t-1)&1
                const float* hsrc = h_ex + (size_t)(dir * 2 + ((t - 1) & 1)) * (BATCH * UNITS);
                int f = tid * 2, b = f >> 8, u = f & (UNITS - 1);
                unsigned long long v = aloadu64(
                    (const unsigned long long*)&hsrc[(size_t)(bg0 + b) * UNITS + u]);
                *(unsigned long long*)&hL[b][u] = v;
            }
        }
        if (tid >= 960 && tid < 1000) {  // x_t for the 8 batches
            int i = tid - 960, b = i / 5, c = i - b * 5;
            xLe[b][c] = x[((size_t)((bg0 + b) * CCH + c) * SEQ + ts) * 3];
        }
        __syncthreads();

        // z partials: 8 batches x (16 rows x 2 cols) each lane
        float accA[8], accB[8];
        #pragma unroll
        for (int b = 0; b < 8; ++b) {
            float a0 = 0.f, a1 = 0.f;
            const float4* hp = (const float4*)&hL[b][wv * 16];
            #pragma unroll
            for (int q = 0; q < 4; ++q) {
                float4 h4 = hp[q];
                a0 = fmaf(h4.x, wr0[4*q+0], a0); a1 = fmaf(h4.x, wr1[4*q+0], a1);
                a0 = fmaf(h4.y, wr0[4*q+1], a0); a1 = fmaf(h4.y, wr1[4*q+1], a1);
                a0 = fmaf(h4.z, wr0[4*q+2], a0); a1 = fmaf(h4.z, wr1[4*q+2], a1);
                a0 = fmaf(h4.w, wr0[4*q+3], a0); a1 = fmaf(h4.w, wr1[4*q+3], a1);
            }
            accA[b] = a0; accB[b] = a1;
        }
        if (wv >= 8) {
            int s = wv - 8;
            #pragma unroll
            for (int b = 0; b < 8; ++b) {
                zp[s][b][lane] = accA[b];
                zp[s][b][64 + lane] = accB[b];
            }
        }
        __syncthreads();
        if (wv < 8) {
            #pragma unroll
            for (int b = 0; b < 8; ++b) {
                zp[wv][b][lane] += accA[b];
                zp[wv][b][64 + lane] += accB[b];
            }
        }
        __syncthreads();

        if (tid < 256) {
            int b = tid >> 5, u = tid & 31;
            float zi = biasL[u], zf = biasL[32 + u], zg = biasL[64 + u], zo = biasL[96 + u];
            #pragma unroll
            for (int s = 0; s < 8; ++s) {
                zi += zp[s][b][u];       zf += zp[s][b][32 + u];
                zg += zp[s][b][64 + u];  zo += zp[s][b][96 + u];
            }
            #pragma unroll
            for (int c = 0; c < 5; ++c) {
                float xv = xLe[b][c];
                zi = fmaf(xv, WkL[c][u], zi);      zf = fmaf(xv, WkL[c][32 + u], zf);
                zg = fmaf(xv, WkL[c][64 + u], zg); zo = fmaf(xv, WkL[c][96 + u], zo);
            }
            float cn = sigmoidf_(zf) * creg + sigmoidf_(zi) * tanhf_(zg);
            float hn = sigmoidf_(zo) * tanhf_(cn);
            float hprev = hL[b][jsl * 32 + u];
            float h2 = mL[b][ts] ? hn : hprev;
            float c2 = mL[b][ts] ? cn : creg;
            creg = c2;
            astoref(&h_ex[(size_t)(dir * 2 + (t & 1)) * (BATCH * UNITS)
                          + (size_t)(bg0 + b) * UNITS + jsl * 32 + u], h2);
            enc[((size_t)(bg0 + b) * SEQ + ts) * RU + dir * UNITS + jsl * 32 + u] = h2;
        }
        __syncthreads();
        if (tid == 0)
            __hip_atomic_fetch_add(&cnt[dir * 16 + tile], 1, __ATOMIC_RELAXED,
                                   __HIP_MEMORY_SCOPE_AGENT);
    }
    // keep-alive for ldspad (never true: cnt values end at 8*SEQ)
    if (aloadi(&cnt[dir * 16 + tile]) == -1) enc[0] = ldspad[tid & 8191];
}

// ---------------------------------------------------------------------------
// Attention precompute (alpha constant over decoder time). One block/batch.
// ---------------------------------------------------------------------------
__global__ __launch_bounds__(256)
void attn_kernel(const float* __restrict__ enc,
                 const float* __restrict__ W_attn, const float* __restrict__ b_attn,
                 const float* __restrict__ W_dense, const float* __restrict__ b_dense,
                 const float* __restrict__ x,
                 float* __restrict__ attn_ws, float* __restrict__ hidden_ws,
                 float* __restrict__ xbuf, float* __restrict__ xconst)
{
    const int b = blockIdx.x;
    const int tid = threadIdx.x;
    const int lane = tid & 63;
    const int wv = tid >> 6;

    __shared__ float WeL[RU];
    __shared__ float scoresL[SEQ];
    __shared__ float red[256];
    __shared__ float attnL[RU];

    WeL[tid]       = W_attn[CCH + tid];
    WeL[tid + 256] = W_attn[CCH + tid + 256];
    __syncthreads();

    const float* __restrict__ encb = enc + (size_t)b * SEQ * RU;
    const float batt = b_attn[0];

    for (int s = wv; s < SEQ; s += 4) {
        const float* row = encb + (size_t)s * RU;
        float p = 0.0f;
        #pragma unroll
        for (int i = 0; i < 8; ++i) {
            int d = lane * 8 + i;
            p = fmaf(row[d], WeL[d], p);
        }
        #pragma unroll
        for (int o = 32; o; o >>= 1) p += __shfl_xor(p, o);
        if (lane == 0) scoresL[s] = p + batt;
    }
    __syncthreads();

    float m = fmaxf(scoresL[tid], scoresL[tid + 256]);
    red[tid] = m;
    __syncthreads();
    for (int st = 128; st; st >>= 1) {
        if (tid < st) red[tid] = fmaxf(red[tid], red[tid + st]);
        __syncthreads();
    }
    const float mx = red[0];
    __syncthreads();
    float e0 = __expf(scoresL[tid] - mx);
    float e1 = __expf(scoresL[tid + 256] - mx);
    red[tid] = e0 + e1;
    __syncthreads();
    for (int st = 128; st; st >>= 1) {
        if (tid < st) red[tid] += red[tid + st];
        __syncthreads();
    }
    const float sinv = 1.0f / red[0];
    __syncthreads();
    scoresL[tid]       = e0 * sinv;
    scoresL[tid + 256] = e1 * sinv;
    __syncthreads();

    float a0 = 0.0f, a1 = 0.0f;
    for (int s = 0; s < SEQ; ++s) {
        float al = scoresL[s];
        a0 = fmaf(al, encb[(size_t)s * RU + tid], a0);
        a1 = fmaf(al, encb[(size_t)s * RU + tid + 256], a1);
    }
    attn_ws[(size_t)b * RU + tid]       = a0;
    attn_ws[(size_t)b * RU + tid + 256] = a1;
    attnL[tid] = a0;
    attnL[tid + 256] = a1;
    hidden_ws[(size_t)b * RU + tid]       = encb[(size_t)(SEQ - 1) * RU + tid];
    hidden_ws[(size_t)b * RU + tid + 256] = encb[(size_t)(SEQ - 1) * RU + tid + 256];
    if (tid < CCH) xbuf[b * CCH + tid] = x[((size_t)(b * CCH + tid) * SEQ + 0) * 3];
    __syncthreads();

    if (tid < CCH) {
        float acc = b_dense[tid];
        for (int d = 0; d < RU; ++d)
            acc = fmaf(attnL[d], W_dense[(RU + d) * CCH + tid], acc);
        xconst[b * CCH + tid] = acc;
    }
}

// ---------------------------------------------------------------------------
// Decoder: 256 blocks = batch-tile(16, 8 batches) x col-slice(16, 128 cols).
// Wd_r slice in REGISTERS (32 rows x 2 cols per lane = 64 VGPR, asm-pinned).
// waves_per_eu(4,4) + LDS pad >80KB -> VGPR budget 128 -> weights resident.
// ---------------------------------------------------------------------------
__global__ __attribute__((amdgpu_flat_work_group_size(1024, 1024),
                          amdgpu_waves_per_eu(4, 4)))
void decoder_kernel(const float* __restrict__ Wd_k, const float* __restrict__ Wd_r,
                    const float* __restrict__ bd,
                    const float* __restrict__ W_dense,
                    const float* __restrict__ attn_ws, const float* __restrict__ hidden_ws,
                    const float* __restrict__ xbuf, const float* __restrict__ xconst,
                    float* __restrict__ h_ex, int* __restrict__ cnt,
                    float* __restrict__ out)
{
    const int bid  = blockIdx.x;
    const int tile = bid >> 4;
    const int jsl  = bid & 15;
    const int bg0  = tile * 8;
    const int tid  = threadIdx.x;
    const int wv   = tid >> 6;
    const int lane = tid & 63;
    const int g0 = ((lane >> 5) << 9) + jsl * 32 + (lane & 31);

    __shared__ float zp[8][8][128];                 // 32 KB
    __shared__ float __align__(16) hL[8][RU];       // 16 KB
    __shared__ float WdL[RU * CCH];                 // 10 KB (W_dense rows 0..511)
    __shared__ float WkL[5][128];                   // 2.5 KB
    __shared__ float biasL[128];
    __shared__ float attL[8][32];
    __shared__ float xL[8][8];
    __shared__ float xcL[8][8];
    __shared__ float ldspad[4608];                  // 18 KB: forces 1 block/CU

    // ---- one-time staging ----
    for (int i = tid; i < RU * CCH; i += 1024) WdL[i] = W_dense[i];
    for (int i = tid; i < 4608; i += 1024) ldspad[i] = 0.0f;
    if (tid < 128) biasL[tid] = bd[((tid >> 5) << 9) + jsl * 32 + (tid & 31)];
    if (tid >= 128 && tid < 768) {
        int i = tid - 128, c = i >> 7, cl = i & 127;
        WkL[c][cl] = Wd_k[c * 2048 + ((cl >> 5) << 9) + jsl * 32 + (cl & 31)];
    }
    if (tid < 256) {
        int b = tid >> 5, u = tid & 31;
        attL[b][u] = attn_ws[(size_t)(bg0 + b) * RU + jsl * 32 + u];
    }
    if (tid < 64) {
        int b = tid >> 3, c = tid & 7;
        if (c < 5) {
            xL[b][c]  = xbuf[(bg0 + b) * CCH + c];
            xcL[b][c] = xconst[(bg0 + b) * CCH + c];
        }
    }
    {   // t=0 h from hidden_ws (coherent across kernel boundary)
        int f = tid * 4, b = f >> 9, u = f & (RU - 1);
        *(float4*)&hL[b][u] = *(const float4*)&hidden_ws[(size_t)(bg0 + b) * RU + u];
    }
    // weights -> registers (pinned): rows 32*wv..+31, cols g0 and g0+1024
    float wr0[32], wr1[32];
    {
        const float* wbase = Wd_r + (size_t)(wv * 32) * 2048 + g0;
        #pragma unroll
        for (int r = 0; r < 32; ++r) {
            wr0[r] = wbase[(size_t)r * 2048];
            wr1[r] = wbase[(size_t)r * 2048 + 1024];
        }
        #pragma unroll
        for (int r = 0; r < 32; ++r)
            asm volatile("" : "+v"(wr0[r]), "+v"(wr1[r]));
    }
    __syncthreads();

    for (int t = 0; t < SEQ; ++t) {
        if (t > 0) {
            if (tid == 0) {
                int target = 16 * t, guard = 0;
                while (aloadi(&cnt[tile]) < target &&
                       guard < (1 << 26)) { __builtin_amdgcn_s_sleep(1); ++guard; }
            }
            __syncthreads();
            {   // h (8x512) from L3, buffer (t-1)&1
                const float* hsrc = h_ex + (size_t)((t - 1) & 1) * (BATCH * RU);
                int f = tid * 4, b = f >> 9, u = f & (RU - 1);
                const unsigned long long* p =
                    (const unsigned long long*)&hsrc[(size_t)(bg0 + b) * RU + u];
                unsigned long long v0 = aloadu64(p);
                unsigned long long v1 = aloadu64(p + 1);
                *(unsigned long long*)&hL[b][u]     = v0;
                *(unsigned long long*)&hL[b][u + 2] = v1;
            }
            __syncthreads();
            // x_t = xconst + h . W_dense[:512]  (40 wave-reduced items)
            for (int it = wv; it < 40; it += 16) {
                int b = it / 5, c = it - b * 5;
                float p = 0.f;
                #pragma unroll
                for (int q = 0; q < 8; ++q) {
                    int u = lane + (q << 6);
                    p = fmaf(hL[b][u], WdL[u * CCH + c], p);
                }
                #pragma unroll
                for (int o = 32; o; o >>= 1) p += __shfl_xor(p, o);
                if (lane == 0) {
                    float xn = p + xcL[b][c];
                    xL[b][c] = xn;
                    if (jsl == 0)
                        out[(size_t)((bg0 + b) * CCH + c) * (SEQ - 1) + (t - 1)] = xn;
                }
            }
            if (t == 511) break;   // epilogue: out[510] written, done
        }

        // z partials: 8 batches x (32 rows x 2 cols) each lane
        float accA[8], accB[8];
        #pragma unroll
        for (int b = 0; b < 8; ++b) {
            float a0 = 0.f, a1 = 0.f;
            const float4* hp = (const float4*)&hL[b][wv * 32];
            #pragma unroll
            for (int q = 0; q < 8; ++q) {
                float4 h4 = hp[q];
                a0 = fmaf(h4.x, wr0[4*q+0], a0); a1 = fmaf(h4.x, wr1[4*q+0], a1);
                a0 = fmaf(h4.y, wr0[4*q+1], a0); a1 = fmaf(h4.y, wr1[4*q+1], a1);
                a0 = fmaf(h4.z, wr0[4*q+2], a0); a1 = fmaf(h4.z, wr1[4*q+2], a1);
                a0 = fmaf(h4.w, wr0[4*q+3], a0); a1 = fmaf(h4.w, wr1[4*q+3], a1);
            }
            accA[b] = a0; accB[b] = a1;
        }
        if (wv >= 8) {
            int s = wv - 8;
            #pragma unroll
            for (int b = 0; b < 8; ++b) {
                zp[s][b][lane] = accA[b];
                zp[s][b][64 + lane] = accB[b];
            }
        }
        __syncthreads();
        if (wv < 8) {
            #pragma unroll
            for (int b = 0; b < 8; ++b) {
                zp[wv][b][lane] += accA[b];
                zp[wv][b][64 + lane] += accB[b];
            }
        }
        __syncthreads();

        if (tid < 256) {
            int b = tid >> 5, u = tid & 31;
            float zi = biasL[u], zf = biasL[32 + u], zg = biasL[64 + u], zo = biasL[96 + u];
            #pragma unroll
            for (int s = 0; s < 8; ++s) {
                zi += zp[s][b][u];       zf += zp[s][b][32 + u];
                zg += zp[s][b][64 + u];  zo += zp[s][b][96 + u];
            }
            #pragma unroll
            for (int c = 0; c < 5; ++c) {
                float xv = xL[b][c];
                zi = fmaf(xv, WkL[c][u], zi);      zf = fmaf(xv, WkL[c][32 + u], zf);
                zg = fmaf(xv, WkL[c][64 + u], zg); zo = fmaf(xv, WkL[c][96 + u], zo);
            }
            float cn = sigmoidf_(zf) * attL[b][u] + sigmoidf_(zi) * tanhf_(zg);
            float hn = sigmoidf_(zo) * tanhf_(cn);
            astoref(&h_ex[(size_t)(t & 1) * (BATCH * RU)
                          + (size_t)(bg0 + b) * RU + jsl * 32 + u], hn);
        }
        __syncthreads();
        if (tid == 0)
            __hip_atomic_fetch_add(&cnt[tile], 1, __ATOMIC_RELAXED,
                                   __HIP_MEMORY_SCOPE_AGENT);
    }
    // keep-alive for ldspad (never true: cnt values end at 16*(SEQ-1))
    if (aloadi(&cnt[tile]) == -1) out[0] = ldspad[tid & 4095];
}

// ---------------------------------------------------------------------------
extern "C" void kernel_launch(void* const* d_in, const int* in_sizes, int n_in,
                              void* d_out, int out_size, void* d_ws, size_t ws_size,
                              hipStream_t stream)
{
    const float* x       = (const float*)d_in[0];
    const float* Wf_k    = (const float*)d_in[1];
    const float* Wf_r    = (const float*)d_in[2];
    const float* bf      = (const float*)d_in[3];
    const float* Wb_k    = (const float*)d_in[4];
    const float* Wb_r    = (const float*)d_in[5];
    const float* bb      = (const float*)d_in[6];
    const float* Wd_k    = (const float*)d_in[7];
    const float* Wd_r    = (const float*)d_in[8];
    const float* bd      = (const float*)d_in[9];
    const float* W_attn  = (const float*)d_in[10];
    const float* b_attn  = (const float*)d_in[11];
    const float* W_dense = (const float*)d_in[12];
    const float* b_dense = (const float*)d_in[13];
    float* out = (float*)d_out;

    float* ws = (float*)d_ws;
    // persistent (attn -> decoder) region after enc
    float* enc      = ws;                          // [0, ENC_N)
    float* attn_p   = ws + ENC_N;                  // 65536 floats
    float* hidden_p = ws + ENC_N + 65536;          // 65536 floats
    float* xbuf_p   = ws + ENC_N + 131072;         // 640
    float* xconst_p = ws + ENC_N + 131712;         // 640
    // encoder-phase overlays (dead before attn_kernel writes the same region)
    float* h_ex_e   = ws + ENC_N;                  // 2dir x 2buf x 128 x 256 = 131072 floats
    int*   cnt_e    = (int*)(ws + ENC_N + 131072); // 32 ints (later overwritten by xbuf)
    // decoder-phase overlays on dead enc region
    int*   cnt_d    = (int*)ws;                    // 16 ints
    float* h_ex_d   = ws + 4096;                   // 2buf x 128 x 512 = 131072 floats

    hipMemsetAsync(cnt_e, 0, 32 * sizeof(int), stream);
    encoder_kernel<<<256, 1024, 0, stream>>>(x, Wf_k, Wf_r, bf, Wb_k, Wb_r, bb,
                                             enc, h_ex_e, cnt_e);
    attn_kernel<<<BATCH, 256, 0, stream>>>(enc, W_attn, b_attn, W_dense, b_dense, x,
                                           attn_p, hidden_p, xbuf_p, xconst_p);
    hipMemsetAsync(cnt_d, 0, 16 * sizeof(int), stream);
    decoder_kernel<<<256, 1024, 0, stream>>>(Wd_k, Wd_r, bd, W_dense,
                                             attn_p, hidden_p, xbuf_p, xconst_p,
                                             h_ex_d, cnt_d, out);
}

// Round 8
// 5270.274 us; speedup vs baseline: 1.9265x; 1.9265x over previous
//
#include <hip/hip_runtime.h>
#include <math.h>

#define BATCH 128
#define CCH 5
#define SEQ 512
#define UNITS 256
#define RU 512

#define ENC_N 33554432   // BATCH*SEQ*RU floats

__device__ __forceinline__ float sigmoidf_(float v) {
    return 1.0f / (1.0f + __expf(-v));
}
__device__ __forceinline__ float tanhf_(float v) {
    float e = __expf(2.0f * v);
    return 1.0f - 2.0f / (e + 1.0f);
}
__device__ __forceinline__ void astoref(float* p, float v) {
    __hip_atomic_store(p, v, __ATOMIC_RELAXED, __HIP_MEMORY_SCOPE_AGENT);
}
__device__ __forceinline__ void astorei(int* p, int v) {
    __hip_atomic_store(p, v, __ATOMIC_RELAXED, __HIP_MEMORY_SCOPE_AGENT);
}
__device__ __forceinline__ unsigned long long aloadu64(const unsigned long long* p) {
    return __hip_atomic_load(p, __ATOMIC_RELAXED, __HIP_MEMORY_SCOPE_AGENT);
}
__device__ __forceinline__ int aloadi(const int* p) {
    return __hip_atomic_load(p, __ATOMIC_RELAXED, __HIP_MEMORY_SCOPE_AGENT);
}

// ---------------------------------------------------------------------------
// Encoder: 256 blocks = dir(2) x tile(16; 8 batches) x slice(8; 32 units).
// Wr slice register/AGPR-resident. Per-step handshake: per-slice FLAGS (no
// RMW); wave w polls slice w's flag and loads its h-segment as it arrives;
// 16-slot zp removes the add phase (3 barriers/step).
// ---------------------------------------------------------------------------
__global__ __attribute__((amdgpu_flat_work_group_size(1024, 1024),
                          amdgpu_waves_per_eu(4, 4)))
void encoder_kernel(const float* __restrict__ x,
                    const float* __restrict__ Wf_k, const float* __restrict__ Wf_r,
                    const float* __restrict__ bf,
                    const float* __restrict__ Wb_k, const float* __restrict__ Wb_r,
                    const float* __restrict__ bb,
                    float* __restrict__ enc, float* __restrict__ h_ex,
                    int* __restrict__ flags)
{
    const int bid  = blockIdx.x;
    const int dir  = bid >> 7;
    const int tile = (bid >> 3) & 15;
    const int jsl  = bid & 7;
    const int grp  = dir * 16 + tile;
    const int bg0  = tile * 8;
    const float* __restrict__ Wk   = dir ? Wb_k : Wf_k;
    const float* __restrict__ Wr   = dir ? Wb_r : Wf_r;
    const float* __restrict__ bias = dir ? bb : bf;
    const int tid  = threadIdx.x;
    const int wv   = tid >> 6;
    const int lane = tid & 63;
    const int g0 = ((lane >> 5) << 8) + jsl * 32 + (lane & 31);

    __shared__ float zp[16][8][128];                // 64 KB
    __shared__ float __align__(16) hL[8][260];      // 8.3 KB (+4 pad: no bank conf)
    __shared__ float WkL[5][128];
    __shared__ float biasL[128];
    __shared__ unsigned char mL[8][SEQ];            // 4 KB
    __shared__ float xLe[8][8];
    __shared__ float padE[512];                     // 2 KB: forces 1 block/CU

    // ---- one-time staging ----
    for (int i = tid; i < 8 * 260; i += 1024) ((float*)hL)[i] = 0.0f;
    if (tid < 512) padE[tid] = 0.0f;
    if (tid < 128) biasL[tid] = bias[((tid >> 5) << 8) + jsl * 32 + (tid & 31)];
    if (tid >= 128 && tid < 768) {
        int i = tid - 128, c = i >> 7, cl = i & 127;
        WkL[c][cl] = Wk[c * 1024 + ((cl >> 5) << 8) + jsl * 32 + (cl & 31)];
    }
    for (int i = tid; i < 8 * SEQ; i += 1024) {
        int b = i >> 9, tt = i & (SEQ - 1);
        mL[b][tt] = (x[((size_t)((bg0 + b) * CCH) * SEQ + tt) * 3 + 2] != 0.0f) ? 1 : 0;
    }
    // weights -> registers (pinned): rows 16*wv..+15, cols g0 and g0+512
    float wr0[16], wr1[16];
    {
        const float* wbase = Wr + (size_t)(wv * 16) * 1024 + g0;
        #pragma unroll
        for (int r = 0; r < 16; ++r) {
            wr0[r] = wbase[(size_t)r * 1024];
            wr1[r] = wbase[(size_t)r * 1024 + 512];
        }
        #pragma unroll
        for (int r = 0; r < 16; ++r)
            asm volatile("" : "+v"(wr0[r]), "+v"(wr1[r]));
    }
    float creg = 0.0f;
    __syncthreads();

    for (int t = 0; t < SEQ; ++t) {
        const int ts = dir ? (SEQ - 1 - t) : t;
        if (t > 0 && wv < 8) {
            // wave w: spin on slice w's flag, then load its segment
            const int* fp = &flags[(grp * 8 + wv) * 32];
            if (lane == 0) {
                int guard = 0;
                while (aloadi(fp) < t && guard < (1 << 26)) {
                    __builtin_amdgcn_s_sleep(1); ++guard;
                }
            }
            int b = lane >> 3, u = wv * 32 + (lane & 7) * 4;
            const unsigned long long* hsrc = (const unsigned long long*)
                &h_ex[(size_t)(dir * 2 + ((t - 1) & 1)) * (BATCH * UNITS)
                      + (size_t)(bg0 + b) * UNITS + u];
            unsigned long long v0 = aloadu64(hsrc);
            unsigned long long v1 = aloadu64(hsrc + 1);
            *(unsigned long long*)&hL[b][u]     = v0;
            *(unsigned long long*)&hL[b][u + 2] = v1;
        }
        if (tid >= 960 && tid < 1000) {  // wave 15: x_t for the 8 batches
            int i = tid - 960, b = i / 5, c = i - b * 5;
            xLe[b][c] = x[((size_t)((bg0 + b) * CCH + c) * SEQ + ts) * 3];
        }
        __syncthreads();   // B1

        // z partials: 8 batches x (16 rows x 2 cols) per lane
        float accA[8], accB[8];
        #pragma unroll
        for (int b = 0; b < 8; ++b) {
            float a0 = 0.f, a1 = 0.f;
            const float4* hp = (const float4*)&hL[b][wv * 16];
            #pragma unroll
            for (int q = 0; q < 4; ++q) {
                float4 h4 = hp[q];
                a0 = fmaf(h4.x, wr0[4*q+0], a0); a1 = fmaf(h4.x, wr1[4*q+0], a1);
                a0 = fmaf(h4.y, wr0[4*q+1], a0); a1 = fmaf(h4.y, wr1[4*q+1], a1);
                a0 = fmaf(h4.z, wr0[4*q+2], a0); a1 = fmaf(h4.z, wr1[4*q+2], a1);
                a0 = fmaf(h4.w, wr0[4*q+3], a0); a1 = fmaf(h4.w, wr1[4*q+3], a1);
            }
            accA[b] = a0; accB[b] = a1;
        }
        #pragma unroll
        for (int b = 0; b < 8; ++b) {
            zp[wv][b][lane]      = accA[b];
            zp[wv][b][64 + lane] = accB[b];
        }
        __syncthreads();   // B2

        if (tid < 256) {
            int b = tid >> 5, u = tid & 31;
            float zi = biasL[u], zf = biasL[32 + u], zg = biasL[64 + u], zo = biasL[96 + u];
            #pragma unroll
            for (int s = 0; s < 16; ++s) {
                zi += zp[s][b][u];       zf += zp[s][b][32 + u];
                zg += zp[s][b][64 + u];  zo += zp[s][b][96 + u];
            }
            #pragma unroll
            for (int c = 0; c < 5; ++c) {
                float xv = xLe[b][c];
                zi = fmaf(xv, WkL[c][u], zi);      zf = fmaf(xv, WkL[c][32 + u], zf);
                zg = fmaf(xv, WkL[c][64 + u], zg); zo = fmaf(xv, WkL[c][96 + u], zo);
            }
            float cn = sigmoidf_(zf) * creg + sigmoidf_(zi) * tanhf_(zg);
            float hn = sigmoidf_(zo) * tanhf_(cn);
            float hprev = hL[b][jsl * 32 + u];
            float h2 = mL[b][ts] ? hn : hprev;
            float c2 = mL[b][ts] ? cn : creg;
            creg = c2;
            astoref(&h_ex[(size_t)(dir * 2 + (t & 1)) * (BATCH * UNITS)
                          + (size_t)(bg0 + b) * UNITS + jsl * 32 + u], h2);
            enc[((size_t)(bg0 + b) * SEQ + ts) * RU + dir * UNITS + jsl * 32 + u] = h2;
        }
        __syncthreads();   // B3 (drains the h stores)
        if (tid == 0) astorei(&flags[(grp * 8 + jsl) * 32], t + 1);
    }
    // keep-alive for padE (never true)
    if (aloadi(&flags[(grp * 8 + jsl) * 32]) == -1) enc[0] = padE[tid & 511];
}

// ---------------------------------------------------------------------------
// Attention precompute (alpha constant over decoder time). One block/batch.
// ---------------------------------------------------------------------------
__global__ __launch_bounds__(256)
void attn_kernel(const float* __restrict__ enc,
                 const float* __restrict__ W_attn, const float* __restrict__ b_attn,
                 const float* __restrict__ W_dense, const float* __restrict__ b_dense,
                 const float* __restrict__ x,
                 float* __restrict__ attn_ws, float* __restrict__ hidden_ws,
                 float* __restrict__ xbuf, float* __restrict__ xconst)
{
    const int b = blockIdx.x;
    const int tid = threadIdx.x;
    const int lane = tid & 63;
    const int wv = tid >> 6;

    __shared__ float WeL[RU];
    __shared__ float scoresL[SEQ];
    __shared__ float red[256];
    __shared__ float attnL[RU];

    WeL[tid]       = W_attn[CCH + tid];
    WeL[tid + 256] = W_attn[CCH + tid + 256];
    __syncthreads();

    const float* __restrict__ encb = enc + (size_t)b * SEQ * RU;
    const float batt = b_attn[0];

    for (int s = wv; s < SEQ; s += 4) {
        const float* row = encb + (size_t)s * RU;
        float p = 0.0f;
        #pragma unroll
        for (int i = 0; i < 8; ++i) {
            int d = lane * 8 + i;
            p = fmaf(row[d], WeL[d], p);
        }
        #pragma unroll
        for (int o = 32; o; o >>= 1) p += __shfl_xor(p, o);
        if (lane == 0) scoresL[s] = p + batt;
    }
    __syncthreads();

    float m = fmaxf(scoresL[tid], scoresL[tid + 256]);
    red[tid] = m;
    __syncthreads();
    for (int st = 128; st; st >>= 1) {
        if (tid < st) red[tid] = fmaxf(red[tid], red[tid + st]);
        __syncthreads();
    }
    const float mx = red[0];
    __syncthreads();
    float e0 = __expf(scoresL[tid] - mx);
    float e1 = __expf(scoresL[tid + 256] - mx);
    red[tid] = e0 + e1;
    __syncthreads();
    for (int st = 128; st; st >>= 1) {
        if (tid < st) red[tid] += red[tid + st];
        __syncthreads();
    }
    const float sinv = 1.0f / red[0];
    __syncthreads();
    scoresL[tid]       = e0 * sinv;
    scoresL[tid + 256] = e1 * sinv;
    __syncthreads();

    float a0 = 0.0f, a1 = 0.0f;
    for (int s = 0; s < SEQ; ++s) {
        float al = scoresL[s];
        a0 = fmaf(al, encb[(size_t)s * RU + tid], a0);
        a1 = fmaf(al, encb[(size_t)s * RU + tid + 256], a1);
    }
    attn_ws[(size_t)b * RU + tid]       = a0;
    attn_ws[(size_t)b * RU + tid + 256] = a1;
    attnL[tid] = a0;
    attnL[tid + 256] = a1;
    hidden_ws[(size_t)b * RU + tid]       = encb[(size_t)(SEQ - 1) * RU + tid];
    hidden_ws[(size_t)b * RU + tid + 256] = encb[(size_t)(SEQ - 1) * RU + tid + 256];
    if (tid < CCH) xbuf[b * CCH + tid] = x[((size_t)(b * CCH + tid) * SEQ + 0) * 3];
    __syncthreads();

    if (tid < CCH) {
        float acc = b_dense[tid];
        for (int d = 0; d < RU; ++d)
            acc = fmaf(attnL[d], W_dense[(RU + d) * CCH + tid], acc);
        xconst[b * CCH + tid] = acc;
    }
}

// ---------------------------------------------------------------------------
// Decoder: 256 blocks = tile(16; 8 batches) x slice(16; 32 units). Weights
// register/AGPR-resident. Per-slice flags + per-wave poll/load; 16-slot zp;
// 3 barriers/step.
// ---------------------------------------------------------------------------
__global__ __attribute__((amdgpu_flat_work_group_size(1024, 1024),
                          amdgpu_waves_per_eu(4, 4)))
void decoder_kernel(const float* __restrict__ Wd_k, const float* __restrict__ Wd_r,
                    const float* __restrict__ bd,
                    const float* __restrict__ W_dense,
                    const float* __restrict__ attn_ws, const float* __restrict__ hidden_ws,
                    const float* __restrict__ xbuf, const float* __restrict__ xconst,
                    float* __restrict__ h_ex, int* __restrict__ flags,
                    float* __restrict__ out)
{
    const int bid  = blockIdx.x;
    const int tile = bid >> 4;
    const int jsl  = bid & 15;
    const int bg0  = tile * 8;
    const int tid  = threadIdx.x;
    const int wv   = tid >> 6;
    const int lane = tid & 63;
    const int g0 = ((lane >> 5) << 9) + jsl * 32 + (lane & 31);

    __shared__ float zp[16][8][128];                // 64 KB
    __shared__ float __align__(16) hL[8][516];      // 16.5 KB (+4 pad)
    __shared__ float WdL[RU * CCH];                 // 10 KB
    __shared__ float WkL[5][128];                   // 2.5 KB
    __shared__ float biasL[128];
    __shared__ float attL[8][32];
    __shared__ float xL[8][8], xcL[8][8];

    // ---- one-time staging ----
    for (int i = tid; i < RU * CCH; i += 1024) WdL[i] = W_dense[i];
    if (tid < 128) biasL[tid] = bd[((tid >> 5) << 9) + jsl * 32 + (tid & 31)];
    if (tid >= 128 && tid < 768) {
        int i = tid - 128, c = i >> 7, cl = i & 127;
        WkL[c][cl] = Wd_k[c * 2048 + ((cl >> 5) << 9) + jsl * 32 + (cl & 31)];
    }
    if (tid < 256) {
        int b = tid >> 5, u = tid & 31;
        attL[b][u] = attn_ws[(size_t)(bg0 + b) * RU + jsl * 32 + u];
    }
    if (tid < 64) {
        int b = tid >> 3, c = tid & 7;
        if (c < 5) {
            xL[b][c]  = xbuf[(bg0 + b) * CCH + c];
            xcL[b][c] = xconst[(bg0 + b) * CCH + c];
        }
    }
    {   // t=0 h from hidden_ws
        int f = tid * 4, b = f >> 9, u = f & (RU - 1);
        float4 v = *(const float4*)&hidden_ws[(size_t)(bg0 + b) * RU + u];
        *(float4*)&hL[b][u] = v;
    }
    // weights -> registers (pinned): rows 32*wv..+31, cols g0 and g0+1024
    float wr0[32], wr1[32];
    {
        const float* wbase = Wd_r + (size_t)(wv * 32) * 2048 + g0;
        #pragma unroll
        for (int r = 0; r < 32; ++r) {
            wr0[r] = wbase[(size_t)r * 2048];
            wr1[r] = wbase[(size_t)r * 2048 + 1024];
        }
        #pragma unroll
        for (int r = 0; r < 32; ++r)
            asm volatile("" : "+v"(wr0[r]), "+v"(wr1[r]));
    }
    __syncthreads();

    for (int t = 0; t < SEQ; ++t) {
        if (t > 0) {
            // wave w: spin on slice w's flag, load its h segment as it arrives
            const int* fp = &flags[(tile * 16 + wv) * 32];
            if (lane == 0) {
                int guard = 0;
                while (aloadi(fp) < t && guard < (1 << 26)) {
                    __builtin_amdgcn_s_sleep(1); ++guard;
                }
            }
            int b = lane >> 3, u = wv * 32 + (lane & 7) * 4;
            const unsigned long long* hsrc = (const unsigned long long*)
                &h_ex[(size_t)((t - 1) & 1) * (BATCH * RU)
                      + (size_t)(bg0 + b) * RU + u];
            unsigned long long v0 = aloadu64(hsrc);
            unsigned long long v1 = aloadu64(hsrc + 1);
            *(unsigned long long*)&hL[b][u]     = v0;
            *(unsigned long long*)&hL[b][u + 2] = v1;
            __syncthreads();   // B1

            // x_t = xconst + h . W_dense[:512]  (40 wave-reduced items)
            for (int it = wv; it < 40; it += 16) {
                int bb = it / 5, c = it - bb * 5;
                float p = 0.f;
                #pragma unroll
                for (int q = 0; q < 8; ++q) {
                    int uu = lane + (q << 6);
                    p = fmaf(hL[bb][uu], WdL[uu * CCH + c], p);
                }
                #pragma unroll
                for (int o = 32; o; o >>= 1) p += __shfl_xor(p, o);
                if (lane == 0) {
                    float xn = p + xcL[bb][c];
                    xL[bb][c] = xn;
                    if (jsl == 0)
                        out[(size_t)((bg0 + bb) * CCH + c) * (SEQ - 1) + (t - 1)] = xn;
                }
            }
            if (t == 511) break;
        }

        // z partials: 8 batches x (32 rows x 2 cols) per lane
        float accA[8], accB[8];
        #pragma unroll
        for (int b = 0; b < 8; ++b) {
            float a0 = 0.f, a1 = 0.f;
            const float4* hp = (const float4*)&hL[b][wv * 32];
            #pragma unroll
            for (int q = 0; q < 8; ++q) {
                float4 h4 = hp[q];
                a0 = fmaf(h4.x, wr0[4*q+0], a0); a1 = fmaf(h4.x, wr1[4*q+0], a1);
                a0 = fmaf(h4.y, wr0[4*q+1], a0); a1 = fmaf(h4.y, wr1[4*q+1], a1);
                a0 = fmaf(h4.z, wr0[4*q+2], a0); a1 = fmaf(h4.z, wr1[4*q+2], a1);
                a0 = fmaf(h4.w, wr0[4*q+3], a0); a1 = fmaf(h4.w, wr1[4*q+3], a1);
            }
            accA[b] = a0; accB[b] = a1;
        }
        #pragma unroll
        for (int b = 0; b < 8; ++b) {
            zp[wv][b][lane]      = accA[b];
            zp[wv][b][64 + lane] = accB[b];
        }
        __syncthreads();   // B2

        if (tid < 256) {
            int b = tid >> 5, u = tid & 31;
            float zi = biasL[u], zf = biasL[32 + u], zg = biasL[64 + u], zo = biasL[96 + u];
            #pragma unroll
            for (int s = 0; s < 16; ++s) {
                zi += zp[s][b][u];       zf += zp[s][b][32 + u];
                zg += zp[s][b][64 + u];  zo += zp[s][b][96 + u];
            }
            #pragma unroll
            for (int c = 0; c < 5; ++c) {
                float xv = xL[b][c];
                zi = fmaf(xv, WkL[c][u], zi);      zf = fmaf(xv, WkL[c][32 + u], zf);
                zg = fmaf(xv, WkL[c][64 + u], zg); zo = fmaf(xv, WkL[c][96 + u], zo);
            }
            float cn = sigmoidf_(zf) * attL[b][u] + sigmoidf_(zi) * tanhf_(zg);
            float hn = sigmoidf_(zo) * tanhf_(cn);
            astoref(&h_ex[(size_t)(t & 1) * (BATCH * RU)
                          + (size_t)(bg0 + b) * RU + jsl * 32 + u], hn);
        }
        __syncthreads();   // B3 (drains the h stores)
        if (tid == 0) astorei(&flags[(tile * 16 + jsl) * 32], t + 1);
    }
}

// ---------------------------------------------------------------------------
extern "C" void kernel_launch(void* const* d_in, const int* in_sizes, int n_in,
                              void* d_out, int out_size, void* d_ws, size_t ws_size,
                              hipStream_t stream)
{
    const float* x       = (const float*)d_in[0];
    const float* Wf_k    = (const float*)d_in[1];
    const float* Wf_r    = (const float*)d_in[2];
    const float* bf      = (const float*)d_in[3];
    const float* Wb_k    = (const float*)d_in[4];
    const float* Wb_r    = (const float*)d_in[5];
    const float* bb      = (const float*)d_in[6];
    const float* Wd_k    = (const float*)d_in[7];
    const float* Wd_r    = (const float*)d_in[8];
    const float* bd      = (const float*)d_in[9];
    const float* W_attn  = (const float*)d_in[10];
    const float* b_attn  = (const float*)d_in[11];
    const float* W_dense = (const float*)d_in[12];
    const float* b_dense = (const float*)d_in[13];
    float* out = (float*)d_out;

    float* ws = (float*)d_ws;
    // persistent (attn -> decoder) region after enc
    float* enc      = ws;                          // [0, ENC_N)
    float* attn_p   = ws + ENC_N;                  // 65536 floats
    float* hidden_p = ws + ENC_N + 65536;          // 65536 floats
    float* xbuf_p   = ws + ENC_N + 131072;         // 640
    float* xconst_p = ws + ENC_N + 131712;         // 640
    // encoder-phase overlays (dead before attn_kernel writes the same region)
    float* h_ex_e   = ws + ENC_N;                  // 4 x 128 x 256 = 131072 floats
    int*   flag_e   = (int*)(ws + ENC_N + 131072); // 32 grp x 8 x 32 = 8192 ints
    // decoder-phase overlays on dead enc region
    int*   flag_d   = (int*)ws;                    // 16 tile x 16 x 32 = 8192 ints
    float* h_ex_d   = ws + 8192;                   // 2 x 128 x 512 = 131072 floats

    hipMemsetAsync(flag_e, 0, 8192 * sizeof(int), stream);
    encoder_kernel<<<256, 1024, 0, stream>>>(x, Wf_k, Wf_r, bf, Wb_k, Wb_r, bb,
                                             enc, h_ex_e, flag_e);
    attn_kernel<<<BATCH, 256, 0, stream>>>(enc, W_attn, b_attn, W_dense, b_dense, x,
                                           attn_p, hidden_p, xbuf_p, xconst_p);
    hipMemsetAsync(flag_d, 0, 8192 * sizeof(int), stream);
    decoder_kernel<<<256, 1024, 0, stream>>>(Wd_k, Wd_r, bd, W_dense,
                                             attn_p, hidden_p, xbuf_p, xconst_p,
                                             h_ex_d, flag_d, out);
}